// Round 1
// baseline (2871.989 us; speedup 1.0000x reference)
//
#include <hip/hip_runtime.h>

// ---------------------------------------------------------------------------
// GNN 2-layer: m = X@W+b ; agg = segment_sum(m[src], dst) ; out = [agg, m]
// N=50000, E=800000, D=128 (fp32). Out: [N, 256] fp32.
// ws layout: m1 [N*128] | agg1 [N*128]   (51.2 MB total)
// ---------------------------------------------------------------------------

#define D 128
#define TILE_ROWS 32
#define XS_LD (D + 4)   // pad keeps rows 16B-aligned, breaks pow2 stride

union F4 { float4 v; float f[4]; };

// Zero agg1 and the agg half (cols 0..127) of out.
__global__ __launch_bounds__(256) void zero_kernel(float* __restrict__ agg1,
                                                   float* __restrict__ out,
                                                   int n32) {
    int idx = blockIdx.x * 256 + threadIdx.x;   // tasks = N*32 (float4 each)
    if (idx >= n32) return;
    float4 z = {0.f, 0.f, 0.f, 0.f};
    *(float4*)&agg1[(size_t)idx * 4] = z;
    int row = idx >> 5, q = idx & 31;
    *(float4*)&out[(size_t)row * 256 + q * 4] = z;
}

// Y[n][j] = b[j] + sum_k X0[n][k] * W[k][j]  (+ sum_k X1[n][k] * W[128+k][j])
// X0/X1 row stride = 128. Y row stride = ldy (Y pointer pre-offset by caller).
// Block: 256 threads -> 32 rows x 128 cols. Thread: 4 rows x 4 cols.
__global__ __launch_bounds__(256) void gemm_kernel(
    const float* __restrict__ X0, const float* __restrict__ X1,
    const float* __restrict__ W, const float* __restrict__ b,
    float* __restrict__ Y, int ldy, int N)
{
    __shared__ float xs[TILE_ROWS][XS_LD];

    const int tid = threadIdx.x;
    const int col = tid & 31;        // 32 col-groups of 4 -> 128 cols
    const int rg  = tid >> 5;        // 8 row-groups of 4 -> 32 rows
    const int n0  = blockIdx.x * TILE_ROWS;
    const int rg4 = rg * 4;

    F4 acc[4];
    {
        float4 bv = *(const float4*)&b[col * 4];
        #pragma unroll
        for (int p = 0; p < 4; ++p) acc[p].v = bv;
    }

    const int nphase = (X1 != nullptr) ? 2 : 1;
    for (int phase = 0; phase < nphase; ++phase) {
        const float* __restrict__ X  = phase ? X1 : X0;
        const float* __restrict__ Wp = W + (size_t)phase * D * D;

        __syncthreads();   // protect xs reuse across phases
        // stage 32x128 tile of X into LDS (float4, coalesced)
        #pragma unroll
        for (int i = tid; i < TILE_ROWS * 32; i += 256) {
            int row = i >> 5, c4 = i & 31;
            int gr = n0 + row;
            float4 v = {0.f, 0.f, 0.f, 0.f};
            if (gr < N) v = *(const float4*)&X[(size_t)gr * D + c4 * 4];
            *(float4*)&xs[row][c4 * 4] = v;
        }
        __syncthreads();

        for (int k = 0; k < D; k += 4) {
            F4 x0, x1, x2, x3;
            x0.v = *(const float4*)&xs[rg4 + 0][k];
            x1.v = *(const float4*)&xs[rg4 + 1][k];
            x2.v = *(const float4*)&xs[rg4 + 2][k];
            x3.v = *(const float4*)&xs[rg4 + 3][k];
            #pragma unroll
            for (int kk = 0; kk < 4; ++kk) {
                F4 wv;
                wv.v = *(const float4*)&Wp[(size_t)(k + kk) * D + col * 4];
                acc[0].v.x += x0.f[kk] * wv.v.x;
                acc[0].v.y += x0.f[kk] * wv.v.y;
                acc[0].v.z += x0.f[kk] * wv.v.z;
                acc[0].v.w += x0.f[kk] * wv.v.w;
                acc[1].v.x += x1.f[kk] * wv.v.x;
                acc[1].v.y += x1.f[kk] * wv.v.y;
                acc[1].v.z += x1.f[kk] * wv.v.z;
                acc[1].v.w += x1.f[kk] * wv.v.w;
                acc[2].v.x += x2.f[kk] * wv.v.x;
                acc[2].v.y += x2.f[kk] * wv.v.y;
                acc[2].v.z += x2.f[kk] * wv.v.z;
                acc[2].v.w += x2.f[kk] * wv.v.w;
                acc[3].v.x += x3.f[kk] * wv.v.x;
                acc[3].v.y += x3.f[kk] * wv.v.y;
                acc[3].v.z += x3.f[kk] * wv.v.z;
                acc[3].v.w += x3.f[kk] * wv.v.w;
            }
        }
    }

    #pragma unroll
    for (int p = 0; p < 4; ++p) {
        int row = n0 + rg4 + p;
        if (row < N)
            *(float4*)&Y[(size_t)row * ldy + col * 4] = acc[p].v;
    }
}

// For each edge e: agg[dst[e]][:] += msg[src[e]][:]   (128 floats per edge)
// Task = (edge, quarter-of-32-float4): idx>>5 = edge, idx&31 = float4 slot.
__global__ __launch_bounds__(256) void scatter_kernel(
    const float* __restrict__ msg, int msgStride,
    const int* __restrict__ src, const int* __restrict__ dst,
    float* __restrict__ agg, int aggStride, long long total)
{
    long long idx = (long long)blockIdx.x * 256 + threadIdx.x;
    if (idx >= total) return;
    int e    = (int)(idx >> 5);
    int part = (int)(idx & 31);
    int s = src[e];
    int d = dst[e];
    float4 v = *(const float4*)&msg[(size_t)s * msgStride + part * 4];
    float* ap = &agg[(size_t)d * aggStride + part * 4];
    atomicAdd(ap + 0, v.x);
    atomicAdd(ap + 1, v.y);
    atomicAdd(ap + 2, v.z);
    atomicAdd(ap + 3, v.w);
}

extern "C" void kernel_launch(void* const* d_in, const int* in_sizes, int n_in,
                              void* d_out, int out_size, void* d_ws, size_t ws_size,
                              hipStream_t stream) {
    const float* features = (const float*)d_in[0];
    const int*   src      = (const int*)d_in[1];
    const int*   dst      = (const int*)d_in[2];
    const float* W1       = (const float*)d_in[3];
    const float* b1       = (const float*)d_in[4];
    const float* W2       = (const float*)d_in[5];
    const float* b2       = (const float*)d_in[6];
    float* out = (float*)d_out;

    const int N = in_sizes[0] / D;   // 50000
    const int E = in_sizes[1];       // 800000

    float* m1   = (float*)d_ws;
    float* agg1 = m1 + (size_t)N * D;

    // 1. zero agg1 and out[:, 0:128]
    {
        int n32 = N * 32;
        zero_kernel<<<(n32 + 255) / 256, 256, 0, stream>>>(agg1, out, n32);
    }
    // 2. m1 = features @ W1 + b1
    gemm_kernel<<<(N + TILE_ROWS - 1) / TILE_ROWS, 256, 0, stream>>>(
        features, nullptr, W1, b1, m1, D, N);
    // 3. agg1[dst] += m1[src]
    {
        long long total = (long long)E * 32;
        int blocks = (int)((total + 255) / 256);
        scatter_kernel<<<blocks, 256, 0, stream>>>(m1, D, src, dst, agg1, D, total);
    }
    // 4. m2 = agg1 @ W2[:128] + m1 @ W2[128:] + b2 -> out[:, 128:256]
    gemm_kernel<<<(N + TILE_ROWS - 1) / TILE_ROWS, 256, 0, stream>>>(
        agg1, m1, W2, b2, out + D, 2 * D, N);
    // 5. out[:, :128][dst] += out[:, 128:][src]
    {
        long long total = (long long)E * 32;
        int blocks = (int)((total + 255) / 256);
        scatter_kernel<<<blocks, 256, 0, stream>>>(out + D, 2 * D, src, dst,
                                                   out, 2 * D, total);
    }
}

// Round 2
// 395.412 us; speedup vs baseline: 7.2633x; 7.2633x over previous
//
#include <hip/hip_runtime.h>

// ---------------------------------------------------------------------------
// GNN 2-layer: m = X@W+b ; agg = segment_sum(m[src], dst) ; out = [agg, m]
// N=50000, E=800000, D=128 (fp32). Out: [N, 256] fp32.
//
// Strategy: build CSR-by-dst once (graph identical for both layers), then
// replace atomic scatter with per-node gather-sum (one wave per node).
// ws layout: m1 [N*128] f32 | deg [N] | cnt [N] | offs [N+1] | bsums/boffs | bsrc [E]
// agg1 lives temporarily in out[:, :128]; overwritten by agg2 at the end.
// ---------------------------------------------------------------------------

#define D 128
#define TILE_ROWS 32
#define XS_LD (D + 4)

union F4 { float4 v; float f[4]; };

__global__ __launch_bounds__(256) void zero_int_kernel(int* __restrict__ deg,
                                                       int* __restrict__ cnt, int N) {
    int i = blockIdx.x * 256 + threadIdx.x;
    if (i < N) { deg[i] = 0; cnt[i] = 0; }
}

__global__ __launch_bounds__(256) void hist_kernel(const int* __restrict__ dst,
                                                   int* __restrict__ deg, int E) {
    int e = blockIdx.x * 256 + threadIdx.x;
    if (e < E) atomicAdd(&deg[dst[e]], 1);
}

// exclusive scan, stage 1: per-block scan of 256 elements
__global__ __launch_bounds__(256) void scan1_kernel(const int* __restrict__ deg,
                                                    int* __restrict__ offs,
                                                    int* __restrict__ bsums, int N) {
    __shared__ int s[256];
    int tid = threadIdx.x;
    int i = blockIdx.x * 256 + tid;
    int v = (i < N) ? deg[i] : 0;
    s[tid] = v; __syncthreads();
    for (int o = 1; o < 256; o <<= 1) {
        int t = (tid >= o) ? s[tid - o] : 0;
        __syncthreads();
        s[tid] += t;
        __syncthreads();
    }
    if (i < N) offs[i] = s[tid] - v;
    if (tid == 255) bsums[blockIdx.x] = s[255];
}

// stage 2: single-block scan of block sums (looped, carry across chunks)
__global__ __launch_bounds__(256) void scan2_kernel(const int* __restrict__ bsums,
                                                    int* __restrict__ boffs, int nb,
                                                    int* __restrict__ offs, int N) {
    __shared__ int s[256];
    int tid = threadIdx.x;
    int carry = 0;
    for (int base = 0; base < nb; base += 256) {
        int v = (base + tid < nb) ? bsums[base + tid] : 0;
        s[tid] = v; __syncthreads();
        for (int o = 1; o < 256; o <<= 1) {
            int t = (tid >= o) ? s[tid - o] : 0;
            __syncthreads();
            s[tid] += t;
            __syncthreads();
        }
        if (base + tid < nb) boffs[base + tid] = carry + s[tid] - v;
        __syncthreads();
        carry += s[255];
        __syncthreads();
    }
    if (tid == 0) offs[N] = carry;   // == E
}

// stage 3: add block offsets
__global__ __launch_bounds__(256) void scan3_kernel(int* __restrict__ offs,
                                                    const int* __restrict__ boffs, int N) {
    int i = blockIdx.x * 256 + threadIdx.x;
    if (i < N) offs[i] += boffs[i >> 8];
}

// bucket fill: bsrc[offs[dst[e]] + k] = src[e]
__global__ __launch_bounds__(256) void fill_kernel(const int* __restrict__ src,
                                                   const int* __restrict__ dst,
                                                   const int* __restrict__ offs,
                                                   int* __restrict__ cnt,
                                                   int* __restrict__ bsrc, int E) {
    int e = blockIdx.x * 256 + threadIdx.x;
    if (e >= E) return;
    int d = dst[e];
    int p = offs[d] + atomicAdd(&cnt[d], 1);
    bsrc[p] = src[e];
}

// gather-sum: one wave per node. agg[n][:] = sum over incoming edges of msg[src][:]
// lane l holds float2 at columns [2l, 2l+1].
__global__ __launch_bounds__(256) void gather_kernel(
    const float* __restrict__ msg, int msgStride,
    const int* __restrict__ offs, const int* __restrict__ bsrc,
    float* __restrict__ agg, int aggStride, int N)
{
    int wave = (blockIdx.x * 256 + threadIdx.x) >> 6;
    int lane = threadIdx.x & 63;
    if (wave >= N) return;
    int beg = offs[wave], end = offs[wave + 1];
    float2 acc = {0.f, 0.f};
    for (int base = beg; base < end; base += 64) {
        int cnt = end - base; if (cnt > 64) cnt = 64;
        int sidx = (lane < cnt) ? bsrc[base + lane] : 0;
        for (int j = 0; j < cnt; ++j) {
            int s = __shfl(sidx, j, 64);
            float2 v = *(const float2*)&msg[(size_t)s * msgStride + lane * 2];
            acc.x += v.x; acc.y += v.y;
        }
    }
    *(float2*)&agg[(size_t)wave * aggStride + lane * 2] = acc;
}

// Y[n][j] = b[j] + sum_k X0[n][k]*W[k][j] (+ sum_k X1[n][k]*W[128+k][j])
__global__ __launch_bounds__(256) void gemm_kernel(
    const float* __restrict__ X0, int ldx0,
    const float* __restrict__ X1, int ldx1,
    const float* __restrict__ W, const float* __restrict__ b,
    float* __restrict__ Y, int ldy, int N)
{
    __shared__ float xs[TILE_ROWS][XS_LD];

    const int tid = threadIdx.x;
    const int col = tid & 31;
    const int rg  = tid >> 5;
    const int n0  = blockIdx.x * TILE_ROWS;
    const int rg4 = rg * 4;

    F4 acc[4];
    {
        float4 bv = *(const float4*)&b[col * 4];
        #pragma unroll
        for (int p = 0; p < 4; ++p) acc[p].v = bv;
    }

    const int nphase = (X1 != nullptr) ? 2 : 1;
    for (int phase = 0; phase < nphase; ++phase) {
        const float* __restrict__ X  = phase ? X1 : X0;
        const int    ldx             = phase ? ldx1 : ldx0;
        const float* __restrict__ Wp = W + (size_t)phase * D * D;

        __syncthreads();
        #pragma unroll
        for (int i = tid; i < TILE_ROWS * 32; i += 256) {
            int row = i >> 5, c4 = i & 31;
            int gr = n0 + row;
            float4 v = {0.f, 0.f, 0.f, 0.f};
            if (gr < N) v = *(const float4*)&X[(size_t)gr * ldx + c4 * 4];
            *(float4*)&xs[row][c4 * 4] = v;
        }
        __syncthreads();

        for (int k = 0; k < D; k += 4) {
            F4 x0, x1, x2, x3;
            x0.v = *(const float4*)&xs[rg4 + 0][k];
            x1.v = *(const float4*)&xs[rg4 + 1][k];
            x2.v = *(const float4*)&xs[rg4 + 2][k];
            x3.v = *(const float4*)&xs[rg4 + 3][k];
            #pragma unroll
            for (int kk = 0; kk < 4; ++kk) {
                F4 wv;
                wv.v = *(const float4*)&Wp[(size_t)(k + kk) * D + col * 4];
                acc[0].v.x += x0.f[kk] * wv.v.x;
                acc[0].v.y += x0.f[kk] * wv.v.y;
                acc[0].v.z += x0.f[kk] * wv.v.z;
                acc[0].v.w += x0.f[kk] * wv.v.w;
                acc[1].v.x += x1.f[kk] * wv.v.x;
                acc[1].v.y += x1.f[kk] * wv.v.y;
                acc[1].v.z += x1.f[kk] * wv.v.z;
                acc[1].v.w += x1.f[kk] * wv.v.w;
                acc[2].v.x += x2.f[kk] * wv.v.x;
                acc[2].v.y += x2.f[kk] * wv.v.y;
                acc[2].v.z += x2.f[kk] * wv.v.z;
                acc[2].v.w += x2.f[kk] * wv.v.w;
                acc[3].v.x += x3.f[kk] * wv.v.x;
                acc[3].v.y += x3.f[kk] * wv.v.y;
                acc[3].v.z += x3.f[kk] * wv.v.z;
                acc[3].v.w += x3.f[kk] * wv.v.w;
            }
        }
    }

    #pragma unroll
    for (int p = 0; p < 4; ++p) {
        int row = n0 + rg4 + p;
        if (row < N)
            *(float4*)&Y[(size_t)row * ldy + col * 4] = acc[p].v;
    }
}

extern "C" void kernel_launch(void* const* d_in, const int* in_sizes, int n_in,
                              void* d_out, int out_size, void* d_ws, size_t ws_size,
                              hipStream_t stream) {
    const float* features = (const float*)d_in[0];
    const int*   src      = (const int*)d_in[1];
    const int*   dst      = (const int*)d_in[2];
    const float* W1       = (const float*)d_in[3];
    const float* b1       = (const float*)d_in[4];
    const float* W2       = (const float*)d_in[5];
    const float* b2       = (const float*)d_in[6];
    float* out = (float*)d_out;

    const int N = in_sizes[0] / D;   // 50000
    const int E = in_sizes[1];       // 800000

    // ws carve-up
    float* m1   = (float*)d_ws;                  // N*D floats
    int*   deg  = (int*)(m1 + (size_t)N * D);    // N
    int*   cnt  = deg + N;                       // N
    int*   offs = cnt + N;                       // N+1
    int*   bsums= offs + N + 1;                  // up to 1024
    int*   boffs= bsums + 1024;                  // up to 1024
    int*   bsrc = boffs + 1024;                  // E

    const int nb = (N + 255) / 256;

    // --- build CSR by dst (shared by both layers) ---
    zero_int_kernel<<<nb, 256, 0, stream>>>(deg, cnt, N);
    hist_kernel<<<(E + 255) / 256, 256, 0, stream>>>(dst, deg, E);
    scan1_kernel<<<nb, 256, 0, stream>>>(deg, offs, bsums, N);
    scan2_kernel<<<1, 256, 0, stream>>>(bsums, boffs, nb, offs, N);
    scan3_kernel<<<nb, 256, 0, stream>>>(offs, boffs, N);
    fill_kernel<<<(E + 255) / 256, 256, 0, stream>>>(src, dst, offs, cnt, bsrc, E);

    // --- layer 1 ---
    gemm_kernel<<<(N + TILE_ROWS - 1) / TILE_ROWS, 256, 0, stream>>>(
        features, D, nullptr, 0, W1, b1, m1, D, N);
    // agg1 -> out[:, :128] (temporary home; overwritten by agg2 later)
    gather_kernel<<<(N * 64 + 255) / 256, 256, 0, stream>>>(
        m1, D, offs, bsrc, out, 2 * D, N);

    // --- layer 2 ---
    // m2 = agg1 @ W2[:128] + m1 @ W2[128:] + b2 -> out[:, 128:]
    gemm_kernel<<<(N + TILE_ROWS - 1) / TILE_ROWS, 256, 0, stream>>>(
        out, 2 * D, m1, D, W2, b2, out + D, 2 * D, N);
    // agg2 -> out[:, :128]  (reads out[:,128:], writes out[:, :128]; disjoint)
    gather_kernel<<<(N * 64 + 255) / 256, 256, 0, stream>>>(
        out + D, 2 * D, offs, bsrc, out, 2 * D, N);
}

// Round 3
// 308.575 us; speedup vs baseline: 9.3073x; 1.2814x over previous
//
#include <hip/hip_runtime.h>

// ---------------------------------------------------------------------------
// GNN 2-layer via bf16 MFMA + CSR gather (no atomics in hot path).
//   m1 = bf16(X @ W1 + b1)            [MFMA, fp32 acc]
//   agg1 = bf16(seg_sum m1[src])      [gather, fp32 acc]
//   m2 = [agg1,m1] @ W2 + b2          [MFMA] -> out[:,128:] fp32 + bf16 copy
//   agg2 = seg_sum m2[src]            [gather] -> out[:,:128] fp32
// ws: m1bf | agg1bf | m2bf | W1p | W2p | CSR ints
// ---------------------------------------------------------------------------

#define D 128

typedef __attribute__((ext_vector_type(8))) short short8;
typedef __attribute__((ext_vector_type(4))) float float4v;
typedef unsigned short ushort_t;
typedef unsigned int uint_t;

static __device__ __forceinline__ ushort_t f2bf(float f) {
    uint_t u = __builtin_bit_cast(uint_t, f);
    u += 0x7FFFu + ((u >> 16) & 1u);           // RNE
    return (ushort_t)(u >> 16);
}

// ---------------- W packing: B-fragment layout ------------------------------
// frag for (kb, cg, lane): 8 bf16 = W[kb*32 + (lane>>4)*8 + j][cg*16 + (lane&15)]
__global__ __launch_bounds__(256) void pack_w(const float* __restrict__ W,
                                              ushort_t* __restrict__ Wp, int KB) {
    int t = blockIdx.x * 256 + threadIdx.x;
    if (t >= KB * 8 * 64) return;
    int lane = t & 63, cg = (t >> 6) & 7, kb = t >> 9;
    int krow = kb * 32 + (lane >> 4) * 8;
    int col  = cg * 16 + (lane & 15);
    #pragma unroll
    for (int j = 0; j < 8; ++j)
        Wp[(size_t)t * 8 + j] = f2bf(W[(size_t)(krow + j) * D + col]);
}

// ---------------- CSR build (same as round 2) -------------------------------
__global__ __launch_bounds__(256) void zero_int_kernel(int* __restrict__ deg,
                                                       int* __restrict__ cnt, int N) {
    int i = blockIdx.x * 256 + threadIdx.x;
    if (i < N) { deg[i] = 0; cnt[i] = 0; }
}

__global__ __launch_bounds__(256) void hist_kernel(const int* __restrict__ dst,
                                                   int* __restrict__ deg, int E) {
    int e = blockIdx.x * 256 + threadIdx.x;
    if (e < E) atomicAdd(&deg[dst[e]], 1);
}

__global__ __launch_bounds__(256) void scan1_kernel(const int* __restrict__ deg,
                                                    int* __restrict__ offs,
                                                    int* __restrict__ bsums, int N) {
    __shared__ int s[256];
    int tid = threadIdx.x;
    int i = blockIdx.x * 256 + tid;
    int v = (i < N) ? deg[i] : 0;
    s[tid] = v; __syncthreads();
    for (int o = 1; o < 256; o <<= 1) {
        int t = (tid >= o) ? s[tid - o] : 0;
        __syncthreads();
        s[tid] += t;
        __syncthreads();
    }
    if (i < N) offs[i] = s[tid] - v;
    if (tid == 255) bsums[blockIdx.x] = s[255];
}

__global__ __launch_bounds__(256) void scan2_kernel(const int* __restrict__ bsums,
                                                    int* __restrict__ boffs, int nb,
                                                    int* __restrict__ offs, int N) {
    __shared__ int s[256];
    int tid = threadIdx.x;
    int carry = 0;
    for (int base = 0; base < nb; base += 256) {
        int v = (base + tid < nb) ? bsums[base + tid] : 0;
        s[tid] = v; __syncthreads();
        for (int o = 1; o < 256; o <<= 1) {
            int t = (tid >= o) ? s[tid - o] : 0;
            __syncthreads();
            s[tid] += t;
            __syncthreads();
        }
        if (base + tid < nb) boffs[base + tid] = carry + s[tid] - v;
        __syncthreads();
        carry += s[255];
        __syncthreads();
    }
    if (tid == 0) offs[N] = carry;
}

__global__ __launch_bounds__(256) void scan3_kernel(int* __restrict__ offs,
                                                    const int* __restrict__ boffs, int N) {
    int i = blockIdx.x * 256 + threadIdx.x;
    if (i < N) offs[i] += boffs[i >> 8];
}

__global__ __launch_bounds__(256) void fill_kernel(const int* __restrict__ src,
                                                   const int* __restrict__ dst,
                                                   const int* __restrict__ offs,
                                                   int* __restrict__ cnt,
                                                   int* __restrict__ bsrc, int E) {
    int e = blockIdx.x * 256 + threadIdx.x;
    if (e >= E) return;
    int d = dst[e];
    int p = offs[d] + atomicAdd(&cnt[d], 1);
    bsrc[p] = src[e];
}

// ---------------- MFMA GEMM 1: fp32 A -> bf16 Y -----------------------------
// block = 256 (4 waves); wave covers 32 rows x 128 cols; K = 128.
__global__ __launch_bounds__(256) void gemm1_mfma(
    const float* __restrict__ X, const ushort_t* __restrict__ Wp,
    const float* __restrict__ bias, ushort_t* __restrict__ Ybf, int N)
{
    const int wave = threadIdx.x >> 6;
    const int lane = threadIdx.x & 63;
    const int quad = lane >> 4;
    const int l16  = lane & 15;
    const int r0   = blockIdx.x * 128 + wave * 32;

    float4v acc[2][8];
    #pragma unroll
    for (int cg = 0; cg < 8; ++cg) {
        float bv = bias[cg * 16 + l16];
        float4v b4 = {bv, bv, bv, bv};
        acc[0][cg] = b4; acc[1][cg] = b4;
    }

    const short8* wp8 = (const short8*)Wp;

    #pragma unroll
    for (int kb = 0; kb < 4; ++kb) {
        const int k0 = kb * 32 + quad * 8;
        short8 a[2];
        #pragma unroll
        for (int rb = 0; rb < 2; ++rb) {
            int row = r0 + rb * 16 + l16;
            if (row >= N) row = N - 1;
            const float* p = &X[(size_t)row * D + k0];
            float4 x0 = *(const float4*)p;
            float4 x1 = *(const float4*)(p + 4);
            short8 s;
            s[0] = (short)f2bf(x0.x); s[1] = (short)f2bf(x0.y);
            s[2] = (short)f2bf(x0.z); s[3] = (short)f2bf(x0.w);
            s[4] = (short)f2bf(x1.x); s[5] = (short)f2bf(x1.y);
            s[6] = (short)f2bf(x1.z); s[7] = (short)f2bf(x1.w);
            a[rb] = s;
        }
        #pragma unroll
        for (int cg = 0; cg < 8; ++cg) {
            short8 b = wp8[(kb * 8 + cg) * 64 + lane];
            acc[0][cg] = __builtin_amdgcn_mfma_f32_16x16x32_bf16(a[0], b, acc[0][cg], 0, 0, 0);
            acc[1][cg] = __builtin_amdgcn_mfma_f32_16x16x32_bf16(a[1], b, acc[1][cg], 0, 0, 0);
        }
    }

    #pragma unroll
    for (int rb = 0; rb < 2; ++rb) {
        int rowb = r0 + rb * 16 + quad * 4;
        #pragma unroll
        for (int cg = 0; cg < 8; ++cg) {
            int col = cg * 16 + l16;
            #pragma unroll
            for (int i = 0; i < 4; ++i) {
                int row = rowb + i;
                if (row < N) Ybf[(size_t)row * D + col] = f2bf(acc[rb][cg][i]);
            }
        }
    }
}

// ---------------- MFMA GEMM 2: bf16 A0/A1 -> fp32 Y + bf16 copy -------------
__global__ __launch_bounds__(256) void gemm2_mfma(
    const ushort_t* __restrict__ A0, const ushort_t* __restrict__ A1,
    const ushort_t* __restrict__ Wp, const float* __restrict__ bias,
    float* __restrict__ Yf,           // out + 128, row stride 256
    ushort_t* __restrict__ Ybf,       // m2 bf16, row stride 128
    int N)
{
    const int wave = threadIdx.x >> 6;
    const int lane = threadIdx.x & 63;
    const int quad = lane >> 4;
    const int l16  = lane & 15;
    const int r0   = blockIdx.x * 128 + wave * 32;

    float4v acc[2][8];
    #pragma unroll
    for (int cg = 0; cg < 8; ++cg) {
        float bv = bias[cg * 16 + l16];
        float4v b4 = {bv, bv, bv, bv};
        acc[0][cg] = b4; acc[1][cg] = b4;
    }

    const short8* wp8 = (const short8*)Wp;

    #pragma unroll
    for (int kb = 0; kb < 8; ++kb) {
        const ushort_t* __restrict__ A = (kb < 4) ? A0 : A1;
        const int k0 = (kb & 3) * 32 + quad * 8;
        short8 a[2];
        #pragma unroll
        for (int rb = 0; rb < 2; ++rb) {
            int row = r0 + rb * 16 + l16;
            if (row >= N) row = N - 1;
            a[rb] = *(const short8*)&A[(size_t)row * D + k0];
        }
        #pragma unroll
        for (int cg = 0; cg < 8; ++cg) {
            short8 b = wp8[(kb * 8 + cg) * 64 + lane];
            acc[0][cg] = __builtin_amdgcn_mfma_f32_16x16x32_bf16(a[0], b, acc[0][cg], 0, 0, 0);
            acc[1][cg] = __builtin_amdgcn_mfma_f32_16x16x32_bf16(a[1], b, acc[1][cg], 0, 0, 0);
        }
    }

    #pragma unroll
    for (int rb = 0; rb < 2; ++rb) {
        int rowb = r0 + rb * 16 + quad * 4;
        #pragma unroll
        for (int cg = 0; cg < 8; ++cg) {
            int col = cg * 16 + l16;
            #pragma unroll
            for (int i = 0; i < 4; ++i) {
                int row = rowb + i;
                if (row < N) {
                    float v = acc[rb][cg][i];
                    Yf[(size_t)row * 256 + col] = v;
                    Ybf[(size_t)row * D + col] = f2bf(v);
                }
            }
        }
    }
}

// ---------------- gather-sum over CSR (bf16 msg) ----------------------------
// one wave per node; lane covers cols [2*lane, 2*lane+1] (one uint).
__global__ __launch_bounds__(256) void gather_bf(
    const ushort_t* __restrict__ msg,            // [N][128] bf16
    const int* __restrict__ offs, const int* __restrict__ bsrc,
    ushort_t* __restrict__ aggB,                 // bf16 out [N][128], or null
    float* __restrict__ aggF,                    // fp32 out (stride 256), or null
    int N)
{
    int node = (blockIdx.x * 256 + threadIdx.x) >> 6;
    int lane = threadIdx.x & 63;
    if (node >= N) return;
    int beg = offs[node], end = offs[node + 1];
    float ax = 0.f, ay = 0.f;
    const uint_t* mp = (const uint_t*)msg;
    for (int base = beg; base < end; base += 64) {
        int cnt = end - base; if (cnt > 64) cnt = 64;
        int sidx = (lane < cnt) ? bsrc[base + lane] : 0;
        for (int j = 0; j < cnt; ++j) {
            int s = __shfl(sidx, j, 64);
            uint_t u = mp[(size_t)s * 64 + lane];
            ax += __builtin_bit_cast(float, u << 16);
            ay += __builtin_bit_cast(float, u & 0xFFFF0000u);
        }
    }
    if (aggB) {
        uint_t o = (uint_t)f2bf(ax) | ((uint_t)f2bf(ay) << 16);
        ((uint_t*)aggB)[(size_t)node * 64 + lane] = o;
    } else {
        float2 v = {ax, ay};
        *(float2*)&aggF[(size_t)node * 256 + lane * 2] = v;
    }
}

// ---------------------------------------------------------------------------
extern "C" void kernel_launch(void* const* d_in, const int* in_sizes, int n_in,
                              void* d_out, int out_size, void* d_ws, size_t ws_size,
                              hipStream_t stream) {
    const float* features = (const float*)d_in[0];
    const int*   src      = (const int*)d_in[1];
    const int*   dst      = (const int*)d_in[2];
    const float* W1       = (const float*)d_in[3];
    const float* b1       = (const float*)d_in[4];
    const float* W2       = (const float*)d_in[5];
    const float* b2       = (const float*)d_in[6];
    float* out = (float*)d_out;

    const int N = in_sizes[0] / D;   // 50000
    const int E = in_sizes[1];       // 800000

    // ws carve-up (ushorts first, then ints; all 16B-aligned)
    ushort_t* m1bf   = (ushort_t*)d_ws;                 // N*D
    ushort_t* agg1bf = m1bf + (size_t)N * D;            // N*D
    ushort_t* m2bf   = agg1bf + (size_t)N * D;          // N*D
    ushort_t* W1p    = m2bf + (size_t)N * D;            // 4*8*64*8 = 16384
    ushort_t* W2p    = W1p + 16384;                     // 8*8*64*8 = 32768
    int* deg   = (int*)(W2p + 32768);
    int* cnt   = deg + N;
    int* offs  = cnt + N;
    int* bsums = offs + N + 1;
    int* boffs = bsums + 1024;
    int* bsrc  = boffs + 1024;

    const int nb = (N + 255) / 256;
    const int gemmBlocks = (N + 127) / 128;

    // W packing
    pack_w<<<(4 * 8 * 64 + 255) / 256, 256, 0, stream>>>(W1, W1p, 4);
    pack_w<<<(8 * 8 * 64 + 255) / 256, 256, 0, stream>>>(W2, W2p, 8);

    // CSR by dst
    zero_int_kernel<<<nb, 256, 0, stream>>>(deg, cnt, N);
    hist_kernel<<<(E + 255) / 256, 256, 0, stream>>>(dst, deg, E);
    scan1_kernel<<<nb, 256, 0, stream>>>(deg, offs, bsums, N);
    scan2_kernel<<<1, 256, 0, stream>>>(bsums, boffs, nb, offs, N);
    scan3_kernel<<<nb, 256, 0, stream>>>(offs, boffs, N);
    fill_kernel<<<(E + 255) / 256, 256, 0, stream>>>(src, dst, offs, cnt, bsrc, E);

    // layer 1
    gemm1_mfma<<<gemmBlocks, 256, 0, stream>>>(features, W1p, b1, m1bf, N);
    gather_bf<<<(N * 64 + 255) / 256, 256, 0, stream>>>(m1bf, offs, bsrc,
                                                        agg1bf, nullptr, N);
    // layer 2
    gemm2_mfma<<<gemmBlocks, 256, 0, stream>>>(agg1bf, m1bf, W2p, b2,
                                               out + D, m2bf, N);
    gather_bf<<<(N * 64 + 255) / 256, 256, 0, stream>>>(m2bf, offs, bsrc,
                                                        nullptr, out, N);
}

// Round 4
// 265.043 us; speedup vs baseline: 10.8359x; 1.1642x over previous
//
#include <hip/hip_runtime.h>

// ---------------------------------------------------------------------------
// GNN 2-layer via bf16 MFMA + CSR gather (no atomics in hot path).
//   m1 = bf16(X @ W1 + b1)            [MFMA, fp32 acc]
//   agg1 = bf16(seg_sum m1[src])      [gather, fp32 acc, 4-way MLP]
//   m2 = [agg1,m1] @ W2 + b2          [MFMA] -> out[:,128:] fp32 + bf16 copy
//   agg2 = seg_sum m2[src]            [gather] -> out[:,:128] fp32
// ws: m1bf | agg1bf | m2bf | W1p | W2p | CSR ints
// ---------------------------------------------------------------------------

#define D 128

typedef __attribute__((ext_vector_type(8))) short short8;
typedef __attribute__((ext_vector_type(4))) float float4v;
typedef unsigned short ushort_t;
typedef unsigned int uint_t;

static __device__ __forceinline__ ushort_t f2bf(float f) {
    uint_t u = __builtin_bit_cast(uint_t, f);
    u += 0x7FFFu + ((u >> 16) & 1u);           // RNE
    return (ushort_t)(u >> 16);
}
static __device__ __forceinline__ float bfhi(uint_t u) {   // high bf16 -> f32
    return __builtin_bit_cast(float, u & 0xFFFF0000u);
}
static __device__ __forceinline__ float bflo(uint_t u) {   // low bf16 -> f32
    return __builtin_bit_cast(float, u << 16);
}

// ---------------- W packing: B-fragment layout (both weights, one launch) ---
// frag for (kb, cg, lane): 8 bf16 = W[kb*32 + (lane>>4)*8 + j][cg*16 + (lane&15)]
__global__ __launch_bounds__(256) void pack_w(const float* __restrict__ W1,
                                              const float* __restrict__ W2,
                                              ushort_t* __restrict__ W1p,
                                              ushort_t* __restrict__ W2p) {
    const int n1 = 4 * 8 * 64;
    const int n2 = 8 * 8 * 64;
    int t = blockIdx.x * 256 + threadIdx.x;
    if (t >= n1 + n2) return;
    const float* W; ushort_t* Wp; int tt;
    if (t < n1) { W = W1; Wp = W1p; tt = t; }
    else        { W = W2; Wp = W2p; tt = t - n1; }
    int lane = tt & 63, cg = (tt >> 6) & 7, kb = tt >> 9;
    int krow = kb * 32 + (lane >> 4) * 8;
    int col  = cg * 16 + (lane & 15);
    #pragma unroll
    for (int j = 0; j < 8; ++j)
        Wp[(size_t)tt * 8 + j] = f2bf(W[(size_t)(krow + j) * D + col]);
}

// ---------------- CSR build ------------------------------------------------
__global__ __launch_bounds__(256) void zero_int_kernel(int* __restrict__ deg,
                                                       int* __restrict__ cnt, int N) {
    int i = blockIdx.x * 256 + threadIdx.x;
    if (i < N) { deg[i] = 0; cnt[i] = 0; }
}

__global__ __launch_bounds__(256) void hist_kernel(const int* __restrict__ dst,
                                                   int* __restrict__ deg, int E) {
    int e = blockIdx.x * 256 + threadIdx.x;
    if (e < E) atomicAdd(&deg[dst[e]], 1);
}

__global__ __launch_bounds__(256) void scan1_kernel(const int* __restrict__ deg,
                                                    int* __restrict__ offs,
                                                    int* __restrict__ bsums, int N) {
    __shared__ int s[256];
    int tid = threadIdx.x;
    int i = blockIdx.x * 256 + tid;
    int v = (i < N) ? deg[i] : 0;
    s[tid] = v; __syncthreads();
    for (int o = 1; o < 256; o <<= 1) {
        int t = (tid >= o) ? s[tid - o] : 0;
        __syncthreads();
        s[tid] += t;
        __syncthreads();
    }
    if (i < N) offs[i] = s[tid] - v;
    if (tid == 255) bsums[blockIdx.x] = s[255];
}

__global__ __launch_bounds__(256) void scan2_kernel(const int* __restrict__ bsums,
                                                    int* __restrict__ boffs, int nb,
                                                    int* __restrict__ offs, int N) {
    __shared__ int s[256];
    int tid = threadIdx.x;
    int carry = 0;
    for (int base = 0; base < nb; base += 256) {
        int v = (base + tid < nb) ? bsums[base + tid] : 0;
        s[tid] = v; __syncthreads();
        for (int o = 1; o < 256; o <<= 1) {
            int t = (tid >= o) ? s[tid - o] : 0;
            __syncthreads();
            s[tid] += t;
            __syncthreads();
        }
        if (base + tid < nb) boffs[base + tid] = carry + s[tid] - v;
        __syncthreads();
        carry += s[255];
        __syncthreads();
    }
    if (tid == 0) offs[N] = carry;
}

__global__ __launch_bounds__(256) void scan3_kernel(int* __restrict__ offs,
                                                    const int* __restrict__ boffs, int N) {
    int i = blockIdx.x * 256 + threadIdx.x;
    if (i < N) offs[i] += boffs[i >> 8];
}

__global__ __launch_bounds__(256) void fill_kernel(const int* __restrict__ src,
                                                   const int* __restrict__ dst,
                                                   const int* __restrict__ offs,
                                                   int* __restrict__ cnt,
                                                   int* __restrict__ bsrc, int E) {
    int e = blockIdx.x * 256 + threadIdx.x;
    if (e >= E) return;
    int d = dst[e];
    int p = offs[d] + atomicAdd(&cnt[d], 1);
    bsrc[p] = src[e];
}

// ---------------- MFMA GEMM 1: fp32 A -> bf16 Y -----------------------------
__global__ __launch_bounds__(256) void gemm1_mfma(
    const float* __restrict__ X, const ushort_t* __restrict__ Wp,
    const float* __restrict__ bias, ushort_t* __restrict__ Ybf, int N)
{
    const int wave = threadIdx.x >> 6;
    const int lane = threadIdx.x & 63;
    const int quad = lane >> 4;
    const int l16  = lane & 15;
    const int r0   = blockIdx.x * 128 + wave * 32;

    float4v acc[2][8];
    #pragma unroll
    for (int cg = 0; cg < 8; ++cg) {
        float bv = bias[cg * 16 + l16];
        float4v b4 = {bv, bv, bv, bv};
        acc[0][cg] = b4; acc[1][cg] = b4;
    }

    const short8* wp8 = (const short8*)Wp;

    #pragma unroll
    for (int kb = 0; kb < 4; ++kb) {
        const int k0 = kb * 32 + quad * 8;
        short8 a[2];
        #pragma unroll
        for (int rb = 0; rb < 2; ++rb) {
            int row = r0 + rb * 16 + l16;
            if (row >= N) row = N - 1;
            const float* p = &X[(size_t)row * D + k0];
            float4 x0 = *(const float4*)p;
            float4 x1 = *(const float4*)(p + 4);
            short8 s;
            s[0] = (short)f2bf(x0.x); s[1] = (short)f2bf(x0.y);
            s[2] = (short)f2bf(x0.z); s[3] = (short)f2bf(x0.w);
            s[4] = (short)f2bf(x1.x); s[5] = (short)f2bf(x1.y);
            s[6] = (short)f2bf(x1.z); s[7] = (short)f2bf(x1.w);
            a[rb] = s;
        }
        #pragma unroll
        for (int cg = 0; cg < 8; ++cg) {
            short8 b = wp8[(kb * 8 + cg) * 64 + lane];
            acc[0][cg] = __builtin_amdgcn_mfma_f32_16x16x32_bf16(a[0], b, acc[0][cg], 0, 0, 0);
            acc[1][cg] = __builtin_amdgcn_mfma_f32_16x16x32_bf16(a[1], b, acc[1][cg], 0, 0, 0);
        }
    }

    #pragma unroll
    for (int rb = 0; rb < 2; ++rb) {
        int rowb = r0 + rb * 16 + quad * 4;
        #pragma unroll
        for (int cg = 0; cg < 8; ++cg) {
            int col = cg * 16 + l16;
            #pragma unroll
            for (int i = 0; i < 4; ++i) {
                int row = rowb + i;
                if (row < N) Ybf[(size_t)row * D + col] = f2bf(acc[rb][cg][i]);
            }
        }
    }
}

// ---------------- MFMA GEMM 2: bf16 A0/A1 -> fp32 Y + bf16 copy -------------
__global__ __launch_bounds__(256) void gemm2_mfma(
    const ushort_t* __restrict__ A0, const ushort_t* __restrict__ A1,
    const ushort_t* __restrict__ Wp, const float* __restrict__ bias,
    float* __restrict__ Yf,           // out + 128, row stride 256
    ushort_t* __restrict__ Ybf,       // m2 bf16, row stride 128
    int N)
{
    const int wave = threadIdx.x >> 6;
    const int lane = threadIdx.x & 63;
    const int quad = lane >> 4;
    const int l16  = lane & 15;
    const int r0   = blockIdx.x * 128 + wave * 32;

    float4v acc[2][8];
    #pragma unroll
    for (int cg = 0; cg < 8; ++cg) {
        float bv = bias[cg * 16 + l16];
        float4v b4 = {bv, bv, bv, bv};
        acc[0][cg] = b4; acc[1][cg] = b4;
    }

    const short8* wp8 = (const short8*)Wp;

    #pragma unroll
    for (int kb = 0; kb < 8; ++kb) {
        const ushort_t* __restrict__ A = (kb < 4) ? A0 : A1;
        const int k0 = (kb & 3) * 32 + quad * 8;
        short8 a[2];
        #pragma unroll
        for (int rb = 0; rb < 2; ++rb) {
            int row = r0 + rb * 16 + l16;
            if (row >= N) row = N - 1;
            a[rb] = *(const short8*)&A[(size_t)row * D + k0];
        }
        #pragma unroll
        for (int cg = 0; cg < 8; ++cg) {
            short8 b = wp8[(kb * 8 + cg) * 64 + lane];
            acc[0][cg] = __builtin_amdgcn_mfma_f32_16x16x32_bf16(a[0], b, acc[0][cg], 0, 0, 0);
            acc[1][cg] = __builtin_amdgcn_mfma_f32_16x16x32_bf16(a[1], b, acc[1][cg], 0, 0, 0);
        }
    }

    #pragma unroll
    for (int rb = 0; rb < 2; ++rb) {
        int rowb = r0 + rb * 16 + quad * 4;
        #pragma unroll
        for (int cg = 0; cg < 8; ++cg) {
            int col = cg * 16 + l16;
            #pragma unroll
            for (int i = 0; i < 4; ++i) {
                int row = rowb + i;
                if (row < N) {
                    float v = acc[rb][cg][i];
                    Yf[(size_t)row * 256 + col] = v;
                    Ybf[(size_t)row * D + col] = f2bf(v);
                }
            }
        }
    }
}

// ---------------- gather-sum over CSR (bf16 msg), 4-way MLP ----------------
// one wave per node; lane covers cols [2*lane, 2*lane+1] (one uint).
__global__ __launch_bounds__(256) void gather_bf(
    const ushort_t* __restrict__ msg,            // [N][128] bf16
    const int* __restrict__ offs, const int* __restrict__ bsrc,
    ushort_t* __restrict__ aggB,                 // bf16 out [N][128], or null
    float* __restrict__ aggF,                    // fp32 out (stride 256), or null
    int N)
{
    int node = (blockIdx.x * 256 + threadIdx.x) >> 6;
    int lane = threadIdx.x & 63;
    if (node >= N) return;
    int beg = offs[node], end = offs[node + 1];
    float ax = 0.f, ay = 0.f;
    const uint_t* mp = (const uint_t*)msg;
    for (int base = beg; base < end; base += 64) {
        int cnt = end - base; if (cnt > 64) cnt = 64;
        int sidx = (lane < cnt) ? bsrc[base + lane] : 0;
        int j = 0;
        for (; j + 4 <= cnt; j += 4) {
            int s0 = __shfl(sidx, j + 0, 64);
            int s1 = __shfl(sidx, j + 1, 64);
            int s2 = __shfl(sidx, j + 2, 64);
            int s3 = __shfl(sidx, j + 3, 64);
            uint_t u0 = mp[(size_t)s0 * 64 + lane];
            uint_t u1 = mp[(size_t)s1 * 64 + lane];
            uint_t u2 = mp[(size_t)s2 * 64 + lane];
            uint_t u3 = mp[(size_t)s3 * 64 + lane];
            ax += bflo(u0); ay += bfhi(u0);
            ax += bflo(u1); ay += bfhi(u1);
            ax += bflo(u2); ay += bfhi(u2);
            ax += bflo(u3); ay += bfhi(u3);
        }
        for (; j < cnt; ++j) {
            int s = __shfl(sidx, j, 64);
            uint_t u = mp[(size_t)s * 64 + lane];
            ax += bflo(u); ay += bfhi(u);
        }
    }
    if (aggB) {
        uint_t o = (uint_t)f2bf(ax) | ((uint_t)f2bf(ay) << 16);
        ((uint_t*)aggB)[(size_t)node * 64 + lane] = o;
    } else {
        float2 v = {ax, ay};
        *(float2*)&aggF[(size_t)node * 256 + lane * 2] = v;
    }
}

// ---------------------------------------------------------------------------
extern "C" void kernel_launch(void* const* d_in, const int* in_sizes, int n_in,
                              void* d_out, int out_size, void* d_ws, size_t ws_size,
                              hipStream_t stream) {
    const float* features = (const float*)d_in[0];
    const int*   src      = (const int*)d_in[1];
    const int*   dst      = (const int*)d_in[2];
    const float* W1       = (const float*)d_in[3];
    const float* b1       = (const float*)d_in[4];
    const float* W2       = (const float*)d_in[5];
    const float* b2       = (const float*)d_in[6];
    float* out = (float*)d_out;

    const int N = in_sizes[0] / D;   // 50000
    const int E = in_sizes[1];       // 800000

    // ws carve-up
    ushort_t* m1bf   = (ushort_t*)d_ws;                 // N*D
    ushort_t* agg1bf = m1bf + (size_t)N * D;            // N*D
    ushort_t* m2bf   = agg1bf + (size_t)N * D;          // N*D
    ushort_t* W1p    = m2bf + (size_t)N * D;            // 16384
    ushort_t* W2p    = W1p + 16384;                     // 32768
    int* deg   = (int*)(W2p + 32768);
    int* cnt   = deg + N;
    int* offs  = cnt + N;
    int* bsums = offs + N + 1;
    int* boffs = bsums + 1024;
    int* bsrc  = boffs + 1024;

    const int nb = (N + 255) / 256;
    const int gemmBlocks = (N + 127) / 128;

    // W packing (both in one launch)
    pack_w<<<(12 * 8 * 64 + 255) / 256, 256, 0, stream>>>(W1, W2, W1p, W2p);

    // CSR by dst
    zero_int_kernel<<<nb, 256, 0, stream>>>(deg, cnt, N);
    hist_kernel<<<(E + 255) / 256, 256, 0, stream>>>(dst, deg, E);
    scan1_kernel<<<nb, 256, 0, stream>>>(deg, offs, bsums, N);
    scan2_kernel<<<1, 256, 0, stream>>>(bsums, boffs, nb, offs, N);
    scan3_kernel<<<nb, 256, 0, stream>>>(offs, boffs, N);
    fill_kernel<<<(E + 255) / 256, 256, 0, stream>>>(src, dst, offs, cnt, bsrc, E);

    // layer 1
    gemm1_mfma<<<gemmBlocks, 256, 0, stream>>>(features, W1p, b1, m1bf, N);
    gather_bf<<<(N * 64 + 255) / 256, 256, 0, stream>>>(m1bf, offs, bsrc,
                                                        agg1bf, nullptr, N);
    // layer 2
    gemm2_mfma<<<gemmBlocks, 256, 0, stream>>>(agg1bf, m1bf, W2p, b2,
                                               out + D, m2bf, N);
    gather_bf<<<(N * 64 + 255) / 256, 256, 0, stream>>>(m2bf, offs, bsrc,
                                                        nullptr, out, N);
}

// Round 5
// 260.955 us; speedup vs baseline: 11.0057x; 1.0157x over previous
//
#include <hip/hip_runtime.h>

// ---------------------------------------------------------------------------
// GNN 2-layer via bf16 MFMA + CSR gather (no atomics in hot path).
//   m1 = bf16(X @ W1 + b1)            [MFMA, fp32 acc]
//   agg1 = bf16(seg_sum m1[src])      [gather, quad-split, 16 rows MLP]
//   m2 = [agg1,m1] @ W2 + b2          [MFMA] -> out[:,128:] fp32 + bf16 copy
//   agg2 = seg_sum m2[src]            [gather] -> out[:,:128] fp32
// CSR build is XCD-partitioned: block b -> dst-range (b&7), edge-chunk (b>>3),
// so cnt atomics / offs reads / bsrc writes stay in one XCD's L2.
// ws: m1bf | agg1bf | m2bf | W1p | W2p | deg | cnt | offs | bsums | boffs | bsrc
// ---------------------------------------------------------------------------

#define D 128
#define NCHUNK 256   // edge chunks per dst-range (grid = 8*NCHUNK for hist/fill)

typedef __attribute__((ext_vector_type(8))) short short8;
typedef __attribute__((ext_vector_type(4))) float float4v;
typedef unsigned short ushort_t;
typedef unsigned int uint_t;

static __device__ __forceinline__ ushort_t f2bf(float f) {
    uint_t u = __builtin_bit_cast(uint_t, f);
    u += 0x7FFFu + ((u >> 16) & 1u);           // RNE
    return (ushort_t)(u >> 16);
}
static __device__ __forceinline__ float bfhi(uint_t u) {
    return __builtin_bit_cast(float, u & 0xFFFF0000u);
}
static __device__ __forceinline__ float bflo(uint_t u) {
    return __builtin_bit_cast(float, u << 16);
}

// ---------------- W packing: B-fragment layout (both weights, one launch) ---
__global__ __launch_bounds__(256) void pack_w(const float* __restrict__ W1,
                                              const float* __restrict__ W2,
                                              ushort_t* __restrict__ W1p,
                                              ushort_t* __restrict__ W2p) {
    const int n1 = 4 * 8 * 64;
    const int n2 = 8 * 8 * 64;
    int t = blockIdx.x * 256 + threadIdx.x;
    if (t >= n1 + n2) return;
    const float* W; ushort_t* Wp; int tt;
    if (t < n1) { W = W1; Wp = W1p; tt = t; }
    else        { W = W2; Wp = W2p; tt = t - n1; }
    int lane = tt & 63, cg = (tt >> 6) & 7, kb = tt >> 9;
    int krow = kb * 32 + (lane >> 4) * 8;
    int col  = cg * 16 + (lane & 15);
    #pragma unroll
    for (int j = 0; j < 8; ++j)
        Wp[(size_t)tt * 8 + j] = f2bf(W[(size_t)(krow + j) * D + col]);
}

// ---------------- CSR build: XCD-partitioned hist + fill --------------------
__global__ __launch_bounds__(256) void hist_part(const int* __restrict__ dst,
                                                 int* __restrict__ deg, int E, int N) {
    int r = blockIdx.x & 7;
    int c = blockIdx.x >> 3;
    int lo = (int)((long long)N * r >> 3);
    int hi = (int)((long long)N * (r + 1) >> 3);
    int chunk = (E + NCHUNK - 1) / NCHUNK;
    int e0 = c * chunk;
    int e1 = e0 + chunk; if (e1 > E) e1 = E;
    for (int e = e0 + threadIdx.x; e < e1; e += 256) {
        int d = dst[e];
        if (d >= lo && d < hi) atomicAdd(&deg[d], 1);
    }
}

__global__ __launch_bounds__(256) void fill_part(const int* __restrict__ src,
                                                 const int* __restrict__ dst,
                                                 const int* __restrict__ offs,
                                                 int* __restrict__ cnt,
                                                 int* __restrict__ bsrc, int E, int N) {
    int r = blockIdx.x & 7;
    int c = blockIdx.x >> 3;
    int lo = (int)((long long)N * r >> 3);
    int hi = (int)((long long)N * (r + 1) >> 3);
    int chunk = (E + NCHUNK - 1) / NCHUNK;
    int e0 = c * chunk;
    int e1 = e0 + chunk; if (e1 > E) e1 = E;
    for (int e = e0 + threadIdx.x; e < e1; e += 256) {
        int d = dst[e];
        if (d >= lo && d < hi) {
            int p = offs[d] + atomicAdd(&cnt[d], 1);
            bsrc[p] = src[e];
        }
    }
}

// ---------------- scans ----------------------------------------------------
__global__ __launch_bounds__(256) void scan1_kernel(const int* __restrict__ deg,
                                                    int* __restrict__ offs,
                                                    int* __restrict__ bsums, int N) {
    __shared__ int s[256];
    int tid = threadIdx.x;
    int i = blockIdx.x * 256 + tid;
    int v = (i < N) ? deg[i] : 0;
    s[tid] = v; __syncthreads();
    for (int o = 1; o < 256; o <<= 1) {
        int t = (tid >= o) ? s[tid - o] : 0;
        __syncthreads();
        s[tid] += t;
        __syncthreads();
    }
    if (i < N) offs[i] = s[tid] - v;
    if (tid == 255) bsums[blockIdx.x] = s[255];
}

__global__ __launch_bounds__(256) void scan2_kernel(const int* __restrict__ bsums,
                                                    int* __restrict__ boffs, int nb,
                                                    int* __restrict__ offs, int N) {
    __shared__ int s[256];
    int tid = threadIdx.x;
    int carry = 0;
    for (int base = 0; base < nb; base += 256) {
        int v = (base + tid < nb) ? bsums[base + tid] : 0;
        s[tid] = v; __syncthreads();
        for (int o = 1; o < 256; o <<= 1) {
            int t = (tid >= o) ? s[tid - o] : 0;
            __syncthreads();
            s[tid] += t;
            __syncthreads();
        }
        if (base + tid < nb) boffs[base + tid] = carry + s[tid] - v;
        __syncthreads();
        carry += s[255];
        __syncthreads();
    }
    if (tid == 0) offs[N] = carry;
}

__global__ __launch_bounds__(256) void scan3_kernel(int* __restrict__ offs,
                                                    const int* __restrict__ boffs, int N) {
    int i = blockIdx.x * 256 + threadIdx.x;
    if (i < N) offs[i] += boffs[i >> 8];
}

// ---------------- MFMA GEMM 1: fp32 A -> bf16 Y -----------------------------
__global__ __launch_bounds__(256) void gemm1_mfma(
    const float* __restrict__ X, const ushort_t* __restrict__ Wp,
    const float* __restrict__ bias, ushort_t* __restrict__ Ybf, int N)
{
    const int wave = threadIdx.x >> 6;
    const int lane = threadIdx.x & 63;
    const int quad = lane >> 4;
    const int l16  = lane & 15;
    const int r0   = blockIdx.x * 128 + wave * 32;

    float4v acc[2][8];
    #pragma unroll
    for (int cg = 0; cg < 8; ++cg) {
        float bv = bias[cg * 16 + l16];
        float4v b4 = {bv, bv, bv, bv};
        acc[0][cg] = b4; acc[1][cg] = b4;
    }

    const short8* wp8 = (const short8*)Wp;

    #pragma unroll
    for (int kb = 0; kb < 4; ++kb) {
        const int k0 = kb * 32 + quad * 8;
        short8 a[2];
        #pragma unroll
        for (int rb = 0; rb < 2; ++rb) {
            int row = r0 + rb * 16 + l16;
            if (row >= N) row = N - 1;
            const float* p = &X[(size_t)row * D + k0];
            float4 x0 = *(const float4*)p;
            float4 x1 = *(const float4*)(p + 4);
            short8 s;
            s[0] = (short)f2bf(x0.x); s[1] = (short)f2bf(x0.y);
            s[2] = (short)f2bf(x0.z); s[3] = (short)f2bf(x0.w);
            s[4] = (short)f2bf(x1.x); s[5] = (short)f2bf(x1.y);
            s[6] = (short)f2bf(x1.z); s[7] = (short)f2bf(x1.w);
            a[rb] = s;
        }
        #pragma unroll
        for (int cg = 0; cg < 8; ++cg) {
            short8 b = wp8[(kb * 8 + cg) * 64 + lane];
            acc[0][cg] = __builtin_amdgcn_mfma_f32_16x16x32_bf16(a[0], b, acc[0][cg], 0, 0, 0);
            acc[1][cg] = __builtin_amdgcn_mfma_f32_16x16x32_bf16(a[1], b, acc[1][cg], 0, 0, 0);
        }
    }

    #pragma unroll
    for (int rb = 0; rb < 2; ++rb) {
        int rowb = r0 + rb * 16 + quad * 4;
        #pragma unroll
        for (int cg = 0; cg < 8; ++cg) {
            int col = cg * 16 + l16;
            #pragma unroll
            for (int i = 0; i < 4; ++i) {
                int row = rowb + i;
                if (row < N) Ybf[(size_t)row * D + col] = f2bf(acc[rb][cg][i]);
            }
        }
    }
}

// ---------------- MFMA GEMM 2: bf16 A0/A1 -> fp32 Y + bf16 copy -------------
__global__ __launch_bounds__(256) void gemm2_mfma(
    const ushort_t* __restrict__ A0, const ushort_t* __restrict__ A1,
    const ushort_t* __restrict__ Wp, const float* __restrict__ bias,
    float* __restrict__ Yf, ushort_t* __restrict__ Ybf, int N)
{
    const int wave = threadIdx.x >> 6;
    const int lane = threadIdx.x & 63;
    const int quad = lane >> 4;
    const int l16  = lane & 15;
    const int r0   = blockIdx.x * 128 + wave * 32;

    float4v acc[2][8];
    #pragma unroll
    for (int cg = 0; cg < 8; ++cg) {
        float bv = bias[cg * 16 + l16];
        float4v b4 = {bv, bv, bv, bv};
        acc[0][cg] = b4; acc[1][cg] = b4;
    }

    const short8* wp8 = (const short8*)Wp;

    #pragma unroll
    for (int kb = 0; kb < 8; ++kb) {
        const ushort_t* __restrict__ A = (kb < 4) ? A0 : A1;
        const int k0 = (kb & 3) * 32 + quad * 8;
        short8 a[2];
        #pragma unroll
        for (int rb = 0; rb < 2; ++rb) {
            int row = r0 + rb * 16 + l16;
            if (row >= N) row = N - 1;
            a[rb] = *(const short8*)&A[(size_t)row * D + k0];
        }
        #pragma unroll
        for (int cg = 0; cg < 8; ++cg) {
            short8 b = wp8[(kb * 8 + cg) * 64 + lane];
            acc[0][cg] = __builtin_amdgcn_mfma_f32_16x16x32_bf16(a[0], b, acc[0][cg], 0, 0, 0);
            acc[1][cg] = __builtin_amdgcn_mfma_f32_16x16x32_bf16(a[1], b, acc[1][cg], 0, 0, 0);
        }
    }

    #pragma unroll
    for (int rb = 0; rb < 2; ++rb) {
        int rowb = r0 + rb * 16 + quad * 4;
        #pragma unroll
        for (int cg = 0; cg < 8; ++cg) {
            int col = cg * 16 + l16;
            #pragma unroll
            for (int i = 0; i < 4; ++i) {
                int row = rowb + i;
                if (row < N) {
                    float v = acc[rb][cg][i];
                    Yf[(size_t)row * 256 + col] = v;
                    Ybf[(size_t)row * D + col] = f2bf(v);
                }
            }
        }
    }
}

// ---------------- gather-sum over CSR (bf16 msg), quad-split ---------------
// one wave per node; quad q (16 lanes) loads full 256B rows (uint4/lane) for
// edges j with (j&3)==q; 4-deep unroll -> 16 rows in flight per wave.
// lane's uint4 covers bf16 cols [8*c16 .. 8*c16+7]. Cross-quad butterfly at end.
__global__ __launch_bounds__(256) void gather_bf(
    const ushort_t* __restrict__ msg,            // [N][128] bf16
    const int* __restrict__ offs, const int* __restrict__ bsrc,
    ushort_t* __restrict__ aggB,                 // bf16 out [N][128], or null
    float* __restrict__ aggF,                    // fp32 out (stride 256), or null
    int N)
{
    int node = (blockIdx.x * 256 + threadIdx.x) >> 6;
    int lane = threadIdx.x & 63;
    if (node >= N) return;
    const int quad = lane >> 4;
    const int c16  = lane & 15;
    int beg = offs[node], end = offs[node + 1];

    float ax[4] = {0.f, 0.f, 0.f, 0.f};
    float ay[4] = {0.f, 0.f, 0.f, 0.f};
    const uint4* mp = (const uint4*)msg;         // 16 uint4 per row

    for (int base = beg; base < end; base += 64) {
        int cnt = end - base; if (cnt > 64) cnt = 64;
        int sidx = bsrc[base + (lane < cnt ? lane : cnt - 1)];
        for (int j0 = 0; j0 < cnt; j0 += 16) {
            #pragma unroll
            for (int t = 0; t < 4; ++t) {
                int e  = j0 + t * 4 + quad;
                int ec = (e < cnt) ? e : cnt - 1;
                int s  = __shfl(sidx, ec, 64);
                uint4 u = mp[(size_t)s * 16 + c16];
                if (e < cnt) {
                    ax[0] += bflo(u.x); ay[0] += bfhi(u.x);
                    ax[1] += bflo(u.y); ay[1] += bfhi(u.y);
                    ax[2] += bflo(u.z); ay[2] += bfhi(u.z);
                    ax[3] += bflo(u.w); ay[3] += bfhi(u.w);
                }
            }
        }
    }

    // reduce across the 4 quads (lanes with same c16)
    #pragma unroll
    for (int k = 0; k < 4; ++k) {
        ax[k] += __shfl_xor(ax[k], 16, 64);
        ax[k] += __shfl_xor(ax[k], 32, 64);
        ay[k] += __shfl_xor(ay[k], 16, 64);
        ay[k] += __shfl_xor(ay[k], 32, 64);
    }

    if (quad == 0) {
        if (aggB) {
            uint4 o;
            o.x = (uint_t)f2bf(ax[0]) | ((uint_t)f2bf(ay[0]) << 16);
            o.y = (uint_t)f2bf(ax[1]) | ((uint_t)f2bf(ay[1]) << 16);
            o.z = (uint_t)f2bf(ax[2]) | ((uint_t)f2bf(ay[2]) << 16);
            o.w = (uint_t)f2bf(ax[3]) | ((uint_t)f2bf(ay[3]) << 16);
            ((uint4*)aggB)[(size_t)node * 16 + c16] = o;
        } else {
            float4 w0 = {ax[0], ay[0], ax[1], ay[1]};
            float4 w1 = {ax[2], ay[2], ax[3], ay[3]};
            float* p = &aggF[(size_t)node * 256 + c16 * 8];
            *(float4*)p = w0;
            *(float4*)(p + 4) = w1;
        }
    }
}

// ---------------------------------------------------------------------------
extern "C" void kernel_launch(void* const* d_in, const int* in_sizes, int n_in,
                              void* d_out, int out_size, void* d_ws, size_t ws_size,
                              hipStream_t stream) {
    const float* features = (const float*)d_in[0];
    const int*   src      = (const int*)d_in[1];
    const int*   dst      = (const int*)d_in[2];
    const float* W1       = (const float*)d_in[3];
    const float* b1       = (const float*)d_in[4];
    const float* W2       = (const float*)d_in[5];
    const float* b2       = (const float*)d_in[6];
    float* out = (float*)d_out;

    const int N = in_sizes[0] / D;   // 50000
    const int E = in_sizes[1];       // 800000

    // ws carve-up
    ushort_t* m1bf   = (ushort_t*)d_ws;                 // N*D
    ushort_t* agg1bf = m1bf + (size_t)N * D;            // N*D
    ushort_t* m2bf   = agg1bf + (size_t)N * D;          // N*D
    ushort_t* W1p    = m2bf + (size_t)N * D;            // 16384
    ushort_t* W2p    = W1p + 16384;                     // 32768
    int* deg   = (int*)(W2p + 32768);
    int* cnt   = deg + N;                               // adjacent to deg
    int* offs  = cnt + N;
    int* bsums = offs + N + 1;
    int* boffs = bsums + 1024;
    int* bsrc  = boffs + 1024;

    const int nb = (N + 255) / 256;
    const int gemmBlocks = (N + 127) / 128;

    // W packing (both in one launch)
    pack_w<<<(12 * 8 * 64 + 255) / 256, 256, 0, stream>>>(W1, W2, W1p, W2p);

    // CSR by dst (XCD-partitioned hist/fill)
    hipMemsetAsync(deg, 0, (size_t)2 * N * sizeof(int), stream);  // deg + cnt
    hist_part<<<8 * NCHUNK, 256, 0, stream>>>(dst, deg, E, N);
    scan1_kernel<<<nb, 256, 0, stream>>>(deg, offs, bsums, N);
    scan2_kernel<<<1, 256, 0, stream>>>(bsums, boffs, nb, offs, N);
    scan3_kernel<<<nb, 256, 0, stream>>>(offs, boffs, N);
    fill_part<<<8 * NCHUNK, 256, 0, stream>>>(src, dst, offs, cnt, bsrc, E, N);

    // layer 1
    gemm1_mfma<<<gemmBlocks, 256, 0, stream>>>(features, W1p, b1, m1bf, N);
    gather_bf<<<(N * 64 + 255) / 256, 256, 0, stream>>>(m1bf, offs, bsrc,
                                                        agg1bf, nullptr, N);
    // layer 2
    gemm2_mfma<<<gemmBlocks, 256, 0, stream>>>(agg1bf, m1bf, W2p, b2,
                                               out + D, m2bf, N);
    gather_bf<<<(N * 64 + 255) / 256, 256, 0, stream>>>(m2bf, offs, bsrc,
                                                        nullptr, out, N);
}